// Round 5
// baseline (511.913 us; speedup 1.0000x reference)
//
#include <hip/hip_runtime.h>
#include <math.h>

#define BB 64
#define HH 1024
#define KK 1024

// d_out layout (floats): h_t | C_t | n_t | m_t
#define OFF_H ((size_t)0)
#define OFF_C ((size_t)BB * HH)
#define OFF_N (OFF_C + (size_t)BB * HH * HH)
#define OFF_M (OFF_N + (size_t)BB * HH)

// GEMM tiling
#define SPLITK 4
#define GBN 32                       // output columns per block
#define GBK 64                       // K per LDS stage
#define NCOLBLK (6 * HH / GBN)       // 192 column-blocks over the 6 stacked gates

typedef float __attribute__((ext_vector_type(4))) f32x4;

__device__ __forceinline__ float dot4v(f32x4 a, f32x4 b) {
    return a[0] * b[0] + a[1] * b[1] + a[2] * b[2] + a[3] * b[3];
}
__device__ __forceinline__ void fma4(float4& a, const float4 x, const float4 w) {
    a.x = fmaf(x.x, w.x, a.x);
    a.y = fmaf(x.y, w.y, a.y);
    a.z = fmaf(x.z, w.z, a.z);
    a.w = fmaf(x.w, w.w, a.w);
}
__device__ __forceinline__ f32x4 ntload4(const float* p) {
    return __builtin_nontemporal_load((const f32x4*)p);
}
__device__ __forceinline__ f32x4 ld4(const float* p) {           // plain load
    return *(const f32x4*)p;
}
__device__ __forceinline__ void ntstore4(float* p, f32x4 v) {
    __builtin_nontemporal_store(v, (f32x4*)p);
}

// Phase A: fp32 GEMM partials. BM=64 (all batches), BN=32, split-K=4 ->
// grid 768 blocks x 256 thr. Thread tile 4 batches x 2 cols, float4 over K.
// W staged in LDS (+4 pad); x broadcast via L1. W read exactly once (24 MB).
__global__ __launch_bounds__(256) void k_gemm(
    const float* __restrict__ x,
    const float* __restrict__ Wi, const float* __restrict__ Wf,
    const float* __restrict__ Wo, const float* __restrict__ Wq,
    const float* __restrict__ Wk, const float* __restrict__ Wv,
    float* __restrict__ Gp)   // [SPLITK][6][BB][HH]
{
    const int cb = blockIdx.x % NCOLBLK;
    const int kc = blockIdx.x / NCOLBLK;
    const int n0 = cb * GBN;
    const int g  = n0 >> 10;             // gate (BN=32 divides 1024 -> uniform)
    const int h0 = n0 & (HH - 1);
    const int k0 = kc * (KK / SPLITK);

    const float* W = (g == 0) ? Wi : (g == 1) ? Wf : (g == 2) ? Wo
                   : (g == 3) ? Wq : (g == 4) ? Wk : Wv;

    const int tid = threadIdx.x;
    const int tn  = tid & 15;            // column-pair index
    const int tm  = tid >> 4;            // batch-quad index

    __shared__ float sW[GBN][GBK + 4];

    float4 acc[4][2];
#pragma unroll
    for (int i = 0; i < 4; ++i)
#pragma unroll
        for (int j = 0; j < 2; ++j) acc[i][j] = make_float4(0.f, 0.f, 0.f, 0.f);

    for (int kk = k0; kk < k0 + KK / SPLITK; kk += GBK) {
        // stage W tile: 32 rows x 64 K = 512 float4, 2 per thread (coalesced, nt)
#pragma unroll
        for (int i = 0; i < 2; ++i) {
            const int idx = tid + i * 256;
            const int c = idx >> 4;
            const int s = idx & 15;
            const f32x4 v = ntload4(W + (size_t)(h0 + c) * KK + kk + s * 4);
            *(f32x4*)&sW[c][s * 4] = v;
        }
        __syncthreads();

        const float4* xr0 = (const float4*)(x + (size_t)(tm * 4 + 0) * KK + kk);
        const float4* xr1 = (const float4*)(x + (size_t)(tm * 4 + 1) * KK + kk);
        const float4* xr2 = (const float4*)(x + (size_t)(tm * 4 + 2) * KK + kk);
        const float4* xr3 = (const float4*)(x + (size_t)(tm * 4 + 3) * KK + kk);
#pragma unroll
        for (int s = 0; s < GBK / 4; ++s) {
            const float4 w0 = *(const float4*)&sW[tn * 2 + 0][s * 4];
            const float4 w1 = *(const float4*)&sW[tn * 2 + 1][s * 4];
            const float4 a0 = xr0[s];
            const float4 a1 = xr1[s];
            const float4 a2 = xr2[s];
            const float4 a3 = xr3[s];
            fma4(acc[0][0], a0, w0); fma4(acc[0][1], a0, w1);
            fma4(acc[1][0], a1, w0); fma4(acc[1][1], a1, w1);
            fma4(acc[2][0], a2, w0); fma4(acc[2][1], a2, w1);
            fma4(acc[3][0], a3, w0); fma4(acc[3][1], a3, w1);
        }
        __syncthreads();
    }

#pragma unroll
    for (int i = 0; i < 4; ++i) {
        const int b = tm * 4 + i;
        const int h = h0 + tn * 2;
        float2 v;
        v.x = acc[i][0].x + acc[i][0].y + acc[i][0].z + acc[i][0].w;
        v.y = acc[i][1].x + acc[i][1].y + acc[i][1].z + acc[i][1].w;
        *(float2*)(Gp + ((size_t)(kc * 6 + g) * BB + b) * HH + h) = v;
    }
}

// Phase B: split-K combine + pointwise epilogue + ni partial per block.
// grid = BB*4 blocks x 256 threads, coalesced along h. No atomics.
__global__ __launch_bounds__(256) void k_epilogue(
    const float* __restrict__ Gp,
    const float* __restrict__ n_in, const float* __restrict__ m_in,
    const float* __restrict__ bi, const float* __restrict__ bf,
    const float* __restrict__ bo, const float* __restrict__ bq,
    const float* __restrict__ bk, const float* __restrict__ bv,
    float* __restrict__ out,
    float* __restrict__ f_s, float* __restrict__ iv_s, float* __restrict__ o_s,
    float* __restrict__ k_s, float* __restrict__ q_s, float* __restrict__ ni4)
{
    const int b = blockIdx.x >> 2;
    const int h = ((blockIdx.x & 3) << 8) + threadIdx.x;
    const size_t bh = (size_t)b * HH + h;

    float gsum[6];
#pragma unroll
    for (int gg = 0; gg < 6; ++gg) {
        float s = 0.f;
#pragma unroll
        for (int kc = 0; kc < SPLITK; ++kc)
            s += Gp[((size_t)(kc * 6 + gg) * BB + b) * HH + h];
        gsum[gg] = s;
    }

    const float it = gsum[0] + bi[h];
    const float ft = gsum[1] + bf[h];
    const float ot = gsum[2] + bo[h];
    const float qt = gsum[3] + bq[h];
    const float kt = (gsum[4] + bk[h]) * 0.03125f;   // / sqrt(1024)
    const float vt = gsum[5] + bv[h];

    const float fsig = 1.0f / (1.0f + expf(-ft));
    const float lsf  = (ft >= 0.0f) ? -log1pf(expf(-ft)) : (ft - log1pf(expf(ft)));
    const float mt   = fmaxf(lsf + m_in[bh], it);
    const float ip   = expf(it - mt);
    const float nt   = fsig * n_in[bh] + ip * kt;
    const float osg  = 1.0f / (1.0f + expf(-ot));

    out[OFF_N + bh] = nt;
    out[OFF_M + bh] = mt;
    f_s[bh]  = fsig;
    iv_s[bh] = ip * vt;
    o_s[bh]  = osg;
    k_s[bh]  = kt;
    q_s[bh]  = qt;

    float d = nt * qt;
#pragma unroll
    for (int off = 32; off >= 1; off >>= 1) d += __shfl_xor(d, off, 64);
    __shared__ float sd[4];
    if ((threadIdx.x & 63) == 0) sd[threadIdx.x >> 6] = d;
    __syncthreads();
    if (threadIdx.x == 0)
        ni4[blockIdx.x] = sd[0] + sd[1] + sd[2] + sd[3];   // partial for (b, quarter)
}

// Kernel 2: C_t = f*C + (i'*v)*k^T fused with the q row-dot.
// Round-1 measured-best structure (depth-1 prefetch, per-row butterfly,
// 8 rows/wave, grid (32,BB)); single change this round: C loads are PLAIN
// (L2-allocating) instead of non-temporal — isolating the nt-load hypothesis.
// Stores remain non-temporal (write-once stream).
__global__ __launch_bounds__(256) void k2_fastweight(
    const float* __restrict__ C,
    const float* __restrict__ f_s, const float* __restrict__ iv_s,
    const float* __restrict__ o_s, const float* __restrict__ k_s,
    const float* __restrict__ q_s, const float* __restrict__ ni4,
    float* __restrict__ out)
{
    const int b    = blockIdx.y;
    const int wave = threadIdx.x >> 6;
    const int lane = threadIdx.x & 63;
    const int i0   = blockIdx.x * 32 + wave * 8;   // first row of this wave's 8

    const float* kr = k_s + (size_t)b * HH;
    const float* qr = q_s + (size_t)b * HH;
    f32x4 kv[4], qv[4];
#pragma unroll
    for (int s = 0; s < 4; ++s) {
        kv[s] = *(const f32x4*)(kr + lane * 4 + s * 256);
        qv[s] = *(const f32x4*)(qr + lane * 4 + s * 256);
    }
    const float inv_div = 1.0f /
        fmaxf(fabsf(ni4[b * 4] + ni4[b * 4 + 1] + ni4[b * 4 + 2] + ni4[b * 4 + 3]), 1.0f);

    const size_t base = (size_t)b * HH + i0;       // first global row index
    float fr[8], ivr[8], ogr[8];
#pragma unroll
    for (int r = 0; r < 8; ++r) {                  // uniform -> scalar loads
        fr[r]  = f_s[base + r];
        ivr[r] = iv_s[base + r];
        ogr[r] = o_s[base + r] * inv_div;
    }

    const float* Crow = C + base * HH;
    float* Ctrow = out + OFF_C + base * HH;

    f32x4 c_cur[4], c_nxt[4];
#pragma unroll
    for (int s = 0; s < 4; ++s) c_cur[s] = ld4(Crow + lane * 4 + s * 256);

#pragma unroll
    for (int r = 0; r < 8; ++r) {
        if (r < 7) {
            const float* Cn = Crow + (size_t)(r + 1) * HH;
#pragma unroll
            for (int s = 0; s < 4; ++s) c_nxt[s] = ld4(Cn + lane * 4 + s * 256);
        }
        const float f  = fr[r];
        const float iv = ivr[r];
        float* Ct = Ctrow + (size_t)r * HH;
        float d = 0.f;
#pragma unroll
        for (int s = 0; s < 4; ++s) {
            f32x4 o;
            o[0] = fmaf(f, c_cur[s][0], iv * kv[s][0]);
            o[1] = fmaf(f, c_cur[s][1], iv * kv[s][1]);
            o[2] = fmaf(f, c_cur[s][2], iv * kv[s][2]);
            o[3] = fmaf(f, c_cur[s][3], iv * kv[s][3]);
            ntstore4(Ct + lane * 4 + s * 256, o);
            d += dot4v(o, qv[s]);
        }
#pragma unroll
        for (int off = 32; off >= 1; off >>= 1) d += __shfl_xor(d, off, 64);
        if (lane == 0) out[OFF_H + base + r] = ogr[r] * d;
#pragma unroll
        for (int s = 0; s < 4; ++s) c_cur[s] = c_nxt[s];
    }
}

extern "C" void kernel_launch(void* const* d_in, const int* in_sizes, int n_in,
                              void* d_out, int out_size, void* d_ws, size_t ws_size,
                              hipStream_t stream) {
    const float* x  = (const float*)d_in[0];
    const float* C  = (const float*)d_in[1];
    const float* n  = (const float*)d_in[2];
    const float* m  = (const float*)d_in[3];
    const float* Wi = (const float*)d_in[4];  const float* bi = (const float*)d_in[5];
    const float* Wf = (const float*)d_in[6];  const float* bf = (const float*)d_in[7];
    const float* Wo = (const float*)d_in[8];  const float* bo = (const float*)d_in[9];
    const float* Wq = (const float*)d_in[10]; const float* bq = (const float*)d_in[11];
    const float* Wk = (const float*)d_in[12]; const float* bk = (const float*)d_in[13];
    const float* Wv = (const float*)d_in[14]; const float* bv = (const float*)d_in[15];

    float* out = (float*)d_out;
    float* ws  = (float*)d_ws;
    float* f_s  = ws;
    float* iv_s = ws + (size_t)BB * HH;
    float* o_s  = ws + (size_t)2 * BB * HH;
    float* k_s  = ws + (size_t)3 * BB * HH;
    float* q_s  = ws + (size_t)4 * BB * HH;
    float* ni4  = ws + (size_t)5 * BB * HH;            // 256 partials
    float* Gp   = ws + (size_t)5 * BB * HH + 256;      // [SPLITK][6][BB][HH] = 6 MB

    k_gemm<<<NCOLBLK * SPLITK, 256, 0, stream>>>(x, Wi, Wf, Wo, Wq, Wk, Wv, Gp);

    k_epilogue<<<BB * 4, 256, 0, stream>>>(Gp, n, m, bi, bf, bo, bq, bk, bv,
                                           out, f_s, iv_s, o_s, k_s, q_s, ni4);

    k2_fastweight<<<dim3(32, BB), 256, 0, stream>>>(C, f_s, iv_s, o_s, k_s, q_s, ni4, out);
}

// Round 6
// 495.899 us; speedup vs baseline: 1.0323x; 1.0323x over previous
//
#include <hip/hip_runtime.h>
#include <math.h>

#define BB 64
#define HH 1024
#define KK 1024

// d_out layout (floats): h_t | C_t | n_t | m_t
#define OFF_H ((size_t)0)
#define OFF_C ((size_t)BB * HH)
#define OFF_N (OFF_C + (size_t)BB * HH * HH)
#define OFF_M (OFF_N + (size_t)BB * HH)

// GEMM tiling
#define SPLITK 4
#define GBN 32                       // output columns per block
#define GBK 64                       // K per LDS stage
#define NCOLBLK (6 * HH / GBN)       // 192 column-blocks over the 6 stacked gates

typedef float __attribute__((ext_vector_type(4))) f32x4;

__device__ __forceinline__ float dot4v(f32x4 a, f32x4 b) {
    return a[0] * b[0] + a[1] * b[1] + a[2] * b[2] + a[3] * b[3];
}
__device__ __forceinline__ void fma4(float4& a, const float4 x, const float4 w) {
    a.x = fmaf(x.x, w.x, a.x);
    a.y = fmaf(x.y, w.y, a.y);
    a.z = fmaf(x.z, w.z, a.z);
    a.w = fmaf(x.w, w.w, a.w);
}
__device__ __forceinline__ f32x4 ntload4(const float* p) {
    return __builtin_nontemporal_load((const f32x4*)p);
}
__device__ __forceinline__ f32x4 ld4(const float* p) {           // plain load
    return *(const f32x4*)p;
}
__device__ __forceinline__ void ntstore4(float* p, f32x4 v) {
    __builtin_nontemporal_store(v, (f32x4*)p);
}

// Phase A: fp32 GEMM partials. BM=64 (all batches), BN=32, split-K=4 ->
// grid 768 blocks x 256 thr. Thread tile 4 batches x 2 cols, float4 over K.
// W staged in LDS (+4 pad); x broadcast via L1. W read exactly once (24 MB).
// UNCHANGED from the measured-best round (est. 15-20 us).
__global__ __launch_bounds__(256) void k_gemm(
    const float* __restrict__ x,
    const float* __restrict__ Wi, const float* __restrict__ Wf,
    const float* __restrict__ Wo, const float* __restrict__ Wq,
    const float* __restrict__ Wk, const float* __restrict__ Wv,
    float* __restrict__ Gp)   // [SPLITK][6][BB][HH]
{
    const int cb = blockIdx.x % NCOLBLK;
    const int kc = blockIdx.x / NCOLBLK;
    const int n0 = cb * GBN;
    const int g  = n0 >> 10;             // gate (BN=32 divides 1024 -> uniform)
    const int h0 = n0 & (HH - 1);
    const int k0 = kc * (KK / SPLITK);

    const float* W = (g == 0) ? Wi : (g == 1) ? Wf : (g == 2) ? Wo
                   : (g == 3) ? Wq : (g == 4) ? Wk : Wv;

    const int tid = threadIdx.x;
    const int tn  = tid & 15;            // column-pair index
    const int tm  = tid >> 4;            // batch-quad index

    __shared__ float sW[GBN][GBK + 4];

    float4 acc[4][2];
#pragma unroll
    for (int i = 0; i < 4; ++i)
#pragma unroll
        for (int j = 0; j < 2; ++j) acc[i][j] = make_float4(0.f, 0.f, 0.f, 0.f);

    for (int kk = k0; kk < k0 + KK / SPLITK; kk += GBK) {
        // stage W tile: 32 rows x 64 K = 512 float4, 2 per thread (coalesced, nt)
#pragma unroll
        for (int i = 0; i < 2; ++i) {
            const int idx = tid + i * 256;
            const int c = idx >> 4;
            const int s = idx & 15;
            const f32x4 v = ntload4(W + (size_t)(h0 + c) * KK + kk + s * 4);
            *(f32x4*)&sW[c][s * 4] = v;
        }
        __syncthreads();

        const float4* xr0 = (const float4*)(x + (size_t)(tm * 4 + 0) * KK + kk);
        const float4* xr1 = (const float4*)(x + (size_t)(tm * 4 + 1) * KK + kk);
        const float4* xr2 = (const float4*)(x + (size_t)(tm * 4 + 2) * KK + kk);
        const float4* xr3 = (const float4*)(x + (size_t)(tm * 4 + 3) * KK + kk);
#pragma unroll
        for (int s = 0; s < GBK / 4; ++s) {
            const float4 w0 = *(const float4*)&sW[tn * 2 + 0][s * 4];
            const float4 w1 = *(const float4*)&sW[tn * 2 + 1][s * 4];
            const float4 a0 = xr0[s];
            const float4 a1 = xr1[s];
            const float4 a2 = xr2[s];
            const float4 a3 = xr3[s];
            fma4(acc[0][0], a0, w0); fma4(acc[0][1], a0, w1);
            fma4(acc[1][0], a1, w0); fma4(acc[1][1], a1, w1);
            fma4(acc[2][0], a2, w0); fma4(acc[2][1], a2, w1);
            fma4(acc[3][0], a3, w0); fma4(acc[3][1], a3, w1);
        }
        __syncthreads();
    }

#pragma unroll
    for (int i = 0; i < 4; ++i) {
        const int b = tm * 4 + i;
        const int h = h0 + tn * 2;
        float2 v;
        v.x = acc[i][0].x + acc[i][0].y + acc[i][0].z + acc[i][0].w;
        v.y = acc[i][1].x + acc[i][1].y + acc[i][1].z + acc[i][1].w;
        *(float2*)(Gp + ((size_t)(kc * 6 + g) * BB + b) * HH + h) = v;
    }
}

// Phase B: split-K combine + pointwise epilogue + ni partial per block.
// grid = BB*4 blocks x 256 threads, coalesced along h. No atomics. UNCHANGED.
__global__ __launch_bounds__(256) void k_epilogue(
    const float* __restrict__ Gp,
    const float* __restrict__ n_in, const float* __restrict__ m_in,
    const float* __restrict__ bi, const float* __restrict__ bf,
    const float* __restrict__ bo, const float* __restrict__ bq,
    const float* __restrict__ bk, const float* __restrict__ bv,
    float* __restrict__ out,
    float* __restrict__ f_s, float* __restrict__ iv_s, float* __restrict__ o_s,
    float* __restrict__ k_s, float* __restrict__ q_s, float* __restrict__ ni4)
{
    const int b = blockIdx.x >> 2;
    const int h = ((blockIdx.x & 3) << 8) + threadIdx.x;
    const size_t bh = (size_t)b * HH + h;

    float gsum[6];
#pragma unroll
    for (int gg = 0; gg < 6; ++gg) {
        float s = 0.f;
#pragma unroll
        for (int kc = 0; kc < SPLITK; ++kc)
            s += Gp[((size_t)(kc * 6 + gg) * BB + b) * HH + h];
        gsum[gg] = s;
    }

    const float it = gsum[0] + bi[h];
    const float ft = gsum[1] + bf[h];
    const float ot = gsum[2] + bo[h];
    const float qt = gsum[3] + bq[h];
    const float kt = (gsum[4] + bk[h]) * 0.03125f;   // / sqrt(1024)
    const float vt = gsum[5] + bv[h];

    const float fsig = 1.0f / (1.0f + expf(-ft));
    const float lsf  = (ft >= 0.0f) ? -log1pf(expf(-ft)) : (ft - log1pf(expf(ft)));
    const float mt   = fmaxf(lsf + m_in[bh], it);
    const float ip   = expf(it - mt);
    const float nt   = fsig * n_in[bh] + ip * kt;
    const float osg  = 1.0f / (1.0f + expf(-ot));

    out[OFF_N + bh] = nt;
    out[OFF_M + bh] = mt;
    f_s[bh]  = fsig;
    iv_s[bh] = ip * vt;
    o_s[bh]  = osg;
    k_s[bh]  = kt;
    q_s[bh]  = qt;

    float d = nt * qt;
#pragma unroll
    for (int off = 32; off >= 1; off >>= 1) d += __shfl_xor(d, off, 64);
    __shared__ float sd[4];
    if ((threadIdx.x & 63) == 0) sd[threadIdx.x >> 6] = d;
    __syncthreads();
    if (threadIdx.x == 0)
        ni4[blockIdx.x] = sd[0] + sd[1] + sd[2] + sd[3];   // partial for (b, quarter)
}

// Kernel 2 v3: C_t = f*C + (i'*v)*k^T fused with the q row-dot.
// ONE ROW PER WAVE, no row loop: maximal TLP (evidence: the R0 block-per-row
// variant at 8 waves/SIMD beat the 8-row ILP variant). Per wave: 8-deep load
// burst (4 nt C + 4 k), fma in-place, 4 nt stores, reload q into the k regs
// (VGPR ~50 -> 8 waves/SIMD via launch_bounds), dot, one butterfly, retire.
// grid (HH/4, BB) = 16384 blocks x 256 thr; 32 waves/CU, ~128 KB in flight/CU.
__global__ __launch_bounds__(256, 8) void k2_fastweight(
    const float* __restrict__ C,
    const float* __restrict__ f_s, const float* __restrict__ iv_s,
    const float* __restrict__ o_s, const float* __restrict__ k_s,
    const float* __restrict__ q_s, const float* __restrict__ ni4,
    float* __restrict__ out)
{
    const int b    = blockIdx.y;
    const int wave = threadIdx.x >> 6;
    const int lane = threadIdx.x & 63;
    const size_t row = (size_t)b * HH + blockIdx.x * 4 + wave;

    const float* Crow = C + row * HH;
    const int col = lane * 4;

    f32x4 a[4], t[4];
#pragma unroll
    for (int s = 0; s < 4; ++s) a[s] = ntload4(Crow + col + s * 256);   // HBM burst
    const float* kr = k_s + (size_t)b * HH;
#pragma unroll
    for (int s = 0; s < 4; ++s) t[s] = ld4(kr + col + s * 256);          // L2 hits

    const float f  = f_s[row];
    const float iv = iv_s[row];

    float* Ct = out + OFF_C + row * HH;
#pragma unroll
    for (int s = 0; s < 4; ++s) {
        a[s][0] = fmaf(f, a[s][0], iv * t[s][0]);
        a[s][1] = fmaf(f, a[s][1], iv * t[s][1]);
        a[s][2] = fmaf(f, a[s][2], iv * t[s][2]);
        a[s][3] = fmaf(f, a[s][3], iv * t[s][3]);
        ntstore4(Ct + col + s * 256, a[s]);
    }

    const float* qr = q_s + (size_t)b * HH;
#pragma unroll
    for (int s = 0; s < 4; ++s) t[s] = ld4(qr + col + s * 256);          // reuse t regs
    float d = 0.f;
#pragma unroll
    for (int s = 0; s < 4; ++s) d += dot4v(a[s], t[s]);
#pragma unroll
    for (int off = 32; off >= 1; off >>= 1) d += __shfl_xor(d, off, 64);

    if (lane == 0) {
        const float nn = fabsf(ni4[b * 4] + ni4[b * 4 + 1] +
                               ni4[b * 4 + 2] + ni4[b * 4 + 3]);
        out[OFF_H + row] = o_s[row] * d / fmaxf(nn, 1.0f);
    }
}

extern "C" void kernel_launch(void* const* d_in, const int* in_sizes, int n_in,
                              void* d_out, int out_size, void* d_ws, size_t ws_size,
                              hipStream_t stream) {
    const float* x  = (const float*)d_in[0];
    const float* C  = (const float*)d_in[1];
    const float* n  = (const float*)d_in[2];
    const float* m  = (const float*)d_in[3];
    const float* Wi = (const float*)d_in[4];  const float* bi = (const float*)d_in[5];
    const float* Wf = (const float*)d_in[6];  const float* bf = (const float*)d_in[7];
    const float* Wo = (const float*)d_in[8];  const float* bo = (const float*)d_in[9];
    const float* Wq = (const float*)d_in[10]; const float* bq = (const float*)d_in[11];
    const float* Wk = (const float*)d_in[12]; const float* bk = (const float*)d_in[13];
    const float* Wv = (const float*)d_in[14]; const float* bv = (const float*)d_in[15];

    float* out = (float*)d_out;
    float* ws  = (float*)d_ws;
    float* f_s  = ws;
    float* iv_s = ws + (size_t)BB * HH;
    float* o_s  = ws + (size_t)2 * BB * HH;
    float* k_s  = ws + (size_t)3 * BB * HH;
    float* q_s  = ws + (size_t)4 * BB * HH;
    float* ni4  = ws + (size_t)5 * BB * HH;            // 256 partials
    float* Gp   = ws + (size_t)5 * BB * HH + 256;      // [SPLITK][6][BB][HH] = 6 MB

    k_gemm<<<NCOLBLK * SPLITK, 256, 0, stream>>>(x, Wi, Wf, Wo, Wq, Wk, Wv, Gp);

    k_epilogue<<<BB * 4, 256, 0, stream>>>(Gp, n, m, bi, bf, bo, bq, bk, bv,
                                           out, f_s, iv_s, o_s, k_s, q_s, ni4);

    k2_fastweight<<<dim3(HH / 4, BB), 256, 0, stream>>>(C, f_s, iv_s, o_s,
                                                        k_s, q_s, ni4, out);
}

// Round 7
// 493.399 us; speedup vs baseline: 1.0375x; 1.0051x over previous
//
#include <hip/hip_runtime.h>
#include <math.h>

#define BB 64
#define HH 1024
#define KK 1024

// d_out layout (floats): h_t | C_t | n_t | m_t
#define OFF_H ((size_t)0)
#define OFF_C ((size_t)BB * HH)
#define OFF_N (OFF_C + (size_t)BB * HH * HH)
#define OFF_M (OFF_N + (size_t)BB * HH)

// GEMM tiling
#define SPLITK 4
#define GBN 32                       // output columns per block
#define GBK 64                       // K per LDS stage
#define NCOLBLK (6 * HH / GBN)       // 192 column-blocks over the 6 stacked gates

typedef float __attribute__((ext_vector_type(4))) f32x4;

__device__ __forceinline__ float dot4v(f32x4 a, f32x4 b) {
    return a[0] * b[0] + a[1] * b[1] + a[2] * b[2] + a[3] * b[3];
}
__device__ __forceinline__ void fma4(float4& a, const float4 x, const float4 w) {
    a.x = fmaf(x.x, w.x, a.x);
    a.y = fmaf(x.y, w.y, a.y);
    a.z = fmaf(x.z, w.z, a.z);
    a.w = fmaf(x.w, w.w, a.w);
}
__device__ __forceinline__ f32x4 ntload4(const float* p) {
    return __builtin_nontemporal_load((const f32x4*)p);
}
__device__ __forceinline__ f32x4 ld4(const float* p) {           // plain load
    return *(const f32x4*)p;
}

// Phase A: fp32 GEMM partials. BM=64 (all batches), BN=32, split-K=4 ->
// grid 768 blocks x 256 thr. Thread tile 4 batches x 2 cols, float4 over K.
// W staged in LDS (+4 pad); x broadcast via L1. W read exactly once (24 MB).
// UNCHANGED (est. ~8-15 us).
__global__ __launch_bounds__(256) void k_gemm(
    const float* __restrict__ x,
    const float* __restrict__ Wi, const float* __restrict__ Wf,
    const float* __restrict__ Wo, const float* __restrict__ Wq,
    const float* __restrict__ Wk, const float* __restrict__ Wv,
    float* __restrict__ Gp)   // [SPLITK][6][BB][HH]
{
    const int cb = blockIdx.x % NCOLBLK;
    const int kc = blockIdx.x / NCOLBLK;
    const int n0 = cb * GBN;
    const int g  = n0 >> 10;             // gate (BN=32 divides 1024 -> uniform)
    const int h0 = n0 & (HH - 1);
    const int k0 = kc * (KK / SPLITK);

    const float* W = (g == 0) ? Wi : (g == 1) ? Wf : (g == 2) ? Wo
                   : (g == 3) ? Wq : (g == 4) ? Wk : Wv;

    const int tid = threadIdx.x;
    const int tn  = tid & 15;            // column-pair index
    const int tm  = tid >> 4;            // batch-quad index

    __shared__ float sW[GBN][GBK + 4];

    float4 acc[4][2];
#pragma unroll
    for (int i = 0; i < 4; ++i)
#pragma unroll
        for (int j = 0; j < 2; ++j) acc[i][j] = make_float4(0.f, 0.f, 0.f, 0.f);

    for (int kk = k0; kk < k0 + KK / SPLITK; kk += GBK) {
        // stage W tile: 32 rows x 64 K = 512 float4, 2 per thread (coalesced, nt)
#pragma unroll
        for (int i = 0; i < 2; ++i) {
            const int idx = tid + i * 256;
            const int c = idx >> 4;
            const int s = idx & 15;
            const f32x4 v = ntload4(W + (size_t)(h0 + c) * KK + kk + s * 4);
            *(f32x4*)&sW[c][s * 4] = v;
        }
        __syncthreads();

        const float4* xr0 = (const float4*)(x + (size_t)(tm * 4 + 0) * KK + kk);
        const float4* xr1 = (const float4*)(x + (size_t)(tm * 4 + 1) * KK + kk);
        const float4* xr2 = (const float4*)(x + (size_t)(tm * 4 + 2) * KK + kk);
        const float4* xr3 = (const float4*)(x + (size_t)(tm * 4 + 3) * KK + kk);
#pragma unroll
        for (int s = 0; s < GBK / 4; ++s) {
            const float4 w0 = *(const float4*)&sW[tn * 2 + 0][s * 4];
            const float4 w1 = *(const float4*)&sW[tn * 2 + 1][s * 4];
            const float4 a0 = xr0[s];
            const float4 a1 = xr1[s];
            const float4 a2 = xr2[s];
            const float4 a3 = xr3[s];
            fma4(acc[0][0], a0, w0); fma4(acc[0][1], a0, w1);
            fma4(acc[1][0], a1, w0); fma4(acc[1][1], a1, w1);
            fma4(acc[2][0], a2, w0); fma4(acc[2][1], a2, w1);
            fma4(acc[3][0], a3, w0); fma4(acc[3][1], a3, w1);
        }
        __syncthreads();
    }

#pragma unroll
    for (int i = 0; i < 4; ++i) {
        const int b = tm * 4 + i;
        const int h = h0 + tn * 2;
        float2 v;
        v.x = acc[i][0].x + acc[i][0].y + acc[i][0].z + acc[i][0].w;
        v.y = acc[i][1].x + acc[i][1].y + acc[i][1].z + acc[i][1].w;
        *(float2*)(Gp + ((size_t)(kc * 6 + g) * BB + b) * HH + h) = v;
    }
}

// Phase B: split-K combine + pointwise epilogue + ni partial per block.
// grid = BB*4 blocks x 256 threads, coalesced along h. No atomics. UNCHANGED.
__global__ __launch_bounds__(256) void k_epilogue(
    const float* __restrict__ Gp,
    const float* __restrict__ n_in, const float* __restrict__ m_in,
    const float* __restrict__ bi, const float* __restrict__ bf,
    const float* __restrict__ bo, const float* __restrict__ bq,
    const float* __restrict__ bk, const float* __restrict__ bv,
    float* __restrict__ out,
    float* __restrict__ f_s, float* __restrict__ iv_s, float* __restrict__ o_s,
    float* __restrict__ k_s, float* __restrict__ q_s, float* __restrict__ ni4)
{
    const int b = blockIdx.x >> 2;
    const int h = ((blockIdx.x & 3) << 8) + threadIdx.x;
    const size_t bh = (size_t)b * HH + h;

    float gsum[6];
#pragma unroll
    for (int gg = 0; gg < 6; ++gg) {
        float s = 0.f;
#pragma unroll
        for (int kc = 0; kc < SPLITK; ++kc)
            s += Gp[((size_t)(kc * 6 + gg) * BB + b) * HH + h];
        gsum[gg] = s;
    }

    const float it = gsum[0] + bi[h];
    const float ft = gsum[1] + bf[h];
    const float ot = gsum[2] + bo[h];
    const float qt = gsum[3] + bq[h];
    const float kt = (gsum[4] + bk[h]) * 0.03125f;   // / sqrt(1024)
    const float vt = gsum[5] + bv[h];

    const float fsig = 1.0f / (1.0f + expf(-ft));
    const float lsf  = (ft >= 0.0f) ? -log1pf(expf(-ft)) : (ft - log1pf(expf(ft)));
    const float mt   = fmaxf(lsf + m_in[bh], it);
    const float ip   = expf(it - mt);
    const float nt   = fsig * n_in[bh] + ip * kt;
    const float osg  = 1.0f / (1.0f + expf(-ot));

    out[OFF_N + bh] = nt;
    out[OFF_M + bh] = mt;
    f_s[bh]  = fsig;
    iv_s[bh] = ip * vt;
    o_s[bh]  = osg;
    k_s[bh]  = kt;
    q_s[bh]  = qt;

    float d = nt * qt;
#pragma unroll
    for (int off = 32; off >= 1; off >>= 1) d += __shfl_xor(d, off, 64);
    __shared__ float sd[4];
    if ((threadIdx.x & 63) == 0) sd[threadIdx.x >> 6] = d;
    __syncthreads();
    if (threadIdx.x == 0)
        ni4[blockIdx.x] = sd[0] + sd[1] + sd[2] + sd[3];   // partial for (b, quarter)
}

// Kernel 2 v4: resurrect the measured-fastest structure (R0: block-per-row,
// one float4/thread, single burst, retire) with only the PROVEN deltas:
//   - nt on the C read (R5 A/B: nt-loads +18 us vs plain)
//   - ni4 partial sum instead of memset+atomicAdd
//   - PLAIN stores (R0 had plain stores and was ~20 us faster than every
//     nt-store variant; this is the isolated nt-store test)
// grid = B*H = 65536 blocks x 256 thr (4 waves); 36-50 VGPR -> 8 waves/SIMD.
__global__ __launch_bounds__(256, 8) void k2_fastweight(
    const float* __restrict__ C,
    const float* __restrict__ f_s, const float* __restrict__ iv_s,
    const float* __restrict__ o_s, const float* __restrict__ k_s,
    const float* __restrict__ q_s, const float* __restrict__ ni4,
    float* __restrict__ out)
{
    const int row = blockIdx.x;          // row = b*H + i
    const int b   = row >> 10;
    const int t   = threadIdx.x;

    const float f  = f_s[row];
    const float iv = iv_s[row];

    const f32x4 c4 = ntload4(C + (size_t)row * HH + t * 4);
    const f32x4 k4 = ld4(k_s + (size_t)b * HH + t * 4);
    const f32x4 q4 = ld4(q_s + (size_t)b * HH + t * 4);

    f32x4 o;
    o[0] = fmaf(f, c4[0], iv * k4[0]);
    o[1] = fmaf(f, c4[1], iv * k4[1]);
    o[2] = fmaf(f, c4[2], iv * k4[2]);
    o[3] = fmaf(f, c4[3], iv * k4[3]);
    *(f32x4*)(out + OFF_C + (size_t)row * HH + t * 4) = o;   // plain store

    float d = dot4v(o, q4);
#pragma unroll
    for (int off = 32; off >= 1; off >>= 1) d += __shfl_xor(d, off, 64);

    __shared__ float sd[4];
    if ((t & 63) == 0) sd[t >> 6] = d;
    __syncthreads();
    if (t == 0) {
        const float tot = sd[0] + sd[1] + sd[2] + sd[3];
        const float nn  = fabsf(ni4[b * 4] + ni4[b * 4 + 1] +
                                ni4[b * 4 + 2] + ni4[b * 4 + 3]);
        out[OFF_H + row] = o_s[row] * tot / fmaxf(nn, 1.0f);
    }
}

extern "C" void kernel_launch(void* const* d_in, const int* in_sizes, int n_in,
                              void* d_out, int out_size, void* d_ws, size_t ws_size,
                              hipStream_t stream) {
    const float* x  = (const float*)d_in[0];
    const float* C  = (const float*)d_in[1];
    const float* n  = (const float*)d_in[2];
    const float* m  = (const float*)d_in[3];
    const float* Wi = (const float*)d_in[4];  const float* bi = (const float*)d_in[5];
    const float* Wf = (const float*)d_in[6];  const float* bf = (const float*)d_in[7];
    const float* Wo = (const float*)d_in[8];  const float* bo = (const float*)d_in[9];
    const float* Wq = (const float*)d_in[10]; const float* bq = (const float*)d_in[11];
    const float* Wk = (const float*)d_in[12]; const float* bk = (const float*)d_in[13];
    const float* Wv = (const float*)d_in[14]; const float* bv = (const float*)d_in[15];

    float* out = (float*)d_out;
    float* ws  = (float*)d_ws;
    float* f_s  = ws;
    float* iv_s = ws + (size_t)BB * HH;
    float* o_s  = ws + (size_t)2 * BB * HH;
    float* k_s  = ws + (size_t)3 * BB * HH;
    float* q_s  = ws + (size_t)4 * BB * HH;
    float* ni4  = ws + (size_t)5 * BB * HH;            // 256 partials
    float* Gp   = ws + (size_t)5 * BB * HH + 256;      // [SPLITK][6][BB][HH] = 6 MB

    k_gemm<<<NCOLBLK * SPLITK, 256, 0, stream>>>(x, Wi, Wf, Wo, Wq, Wk, Wv, Gp);

    k_epilogue<<<BB * 4, 256, 0, stream>>>(Gp, n, m, bi, bf, bo, bq, bk, bv,
                                           out, f_s, iv_s, o_s, k_s, q_s, ni4);

    k2_fastweight<<<BB * HH, 256, 0, stream>>>(C, f_s, iv_s, o_s, k_s, q_s, ni4, out);
}